// Round 9
// baseline (108.624 us; speedup 1.0000x reference)
//
#include <hip/hip_runtime.h>

// Problem constants
#define HWSZ 65536             // 256*256
#define PLANE (3 * HWSZ)       // one batch's [3,H,W]
#define OUTSTRIDE (8 * PLANE)  // one full output tensor [8,3,256,256]
#define MAGIC 0x13572468       // != 0xAAAAAAAA ws poison

// Single-kernel pipeline, 376 blocks x 384 threads:
//   blocks 0..31 : proj for (k,b) -> outs + flag_outs[k*8+b]
//   blocks 0..7  : spin 4 flags -> fcat for b -> param + flag_param[b]
//   blocks 32..375: prefetch x, spin flag_param[b], LUT, render, store
// Producer/consumer visibility via __threadfence + device-scope atomics
// (round-5-proven pattern). All 376 blocks co-resident (cap ~768).
__global__ __launch_bounds__(384) void k_fused(
    const float* __restrict__ f, const float* __restrict__ bf,
    const float* __restrict__ pw1, const float* __restrict__ pb1,
    const float* __restrict__ pw2, const float* __restrict__ pb2,
    const float* __restrict__ fw1, const float* __restrict__ fb1,
    const float* __restrict__ fw2, const float* __restrict__ fb2,
    const float* __restrict__ x, float* __restrict__ out,
    float* __restrict__ ws) {
  __shared__ float smem[2304];  // 9216 B, aliased per phase
  int t = threadIdx.x, blk = blockIdx.x;

  float* outs  = ws;         // [4,8,192]
  float* param = ws + 6144;  // [8,192]
  int* flags = (int*)(ws + 8192);  // flag_outs[i]=flags[i*16], flag_param[b]=flags[(32+b)*16]

  if (blk < 32) {
    // ======== MLP phase A: proj for (k,b) ========
    int k = blk >> 3, b = blk & 7;
    int q = t % 48, s = t / 48;  // s in 0..7
    float* sf  = smem;         // 512
    float* red = smem + 512;   // 8*192
    float* sh  = smem + 2048;  // 192

    const float* feat = ((k & 1) ? bf : f) + b * 512;
    for (int i = t; i < 512; i += 384) sf[i] = feat[i];
    __syncthreads();

    {  // 512 -> 192
      const float4* w = (const float4*)(pw1 + (size_t)k * (512 * 192));
      float4 acc = {0.f, 0.f, 0.f, 0.f};
      int i0 = s * 64;
      for (int r = 0; r < 4; ++r) {
        float4 wv[16];
#pragma unroll
        for (int j = 0; j < 16; ++j)
          wv[j] = w[(size_t)(i0 + r * 16 + j) * 48 + q];
#pragma unroll
        for (int j = 0; j < 16; ++j) {
          float v = sf[i0 + r * 16 + j];
          acc.x = fmaf(v, wv[j].x, acc.x); acc.y = fmaf(v, wv[j].y, acc.y);
          acc.z = fmaf(v, wv[j].z, acc.z); acc.w = fmaf(v, wv[j].w, acc.w);
        }
      }
      ((float4*)(red + s * 192))[q] = acc;
    }
    __syncthreads();
    if (t < 192) {
      float a = pb1[k * 192 + t];
#pragma unroll
      for (int s2 = 0; s2 < 8; ++s2) a += red[s2 * 192 + t];
      sh[t] = fmaxf(a, 0.f);
    }
    __syncthreads();
    {  // 192 -> 192
      const float4* w = (const float4*)(pw2 + (size_t)k * (192 * 192));
      float4 acc = {0.f, 0.f, 0.f, 0.f};
      int i0 = s * 24;
      for (int r = 0; r < 2; ++r) {
        float4 wv[12];
#pragma unroll
        for (int j = 0; j < 12; ++j)
          wv[j] = w[(size_t)(i0 + r * 12 + j) * 48 + q];
#pragma unroll
        for (int j = 0; j < 12; ++j) {
          float v = sh[i0 + r * 12 + j];
          acc.x = fmaf(v, wv[j].x, acc.x); acc.y = fmaf(v, wv[j].y, acc.y);
          acc.z = fmaf(v, wv[j].z, acc.z); acc.w = fmaf(v, wv[j].w, acc.w);
        }
      }
      ((float4*)(red + s * 192))[q] = acc;
    }
    __syncthreads();
    if (t < 192) {
      float a = pb2[k * 192 + t];
#pragma unroll
      for (int s2 = 0; s2 < 8; ++s2) a += red[s2 * 192 + t];
      outs[(k * 8 + b) * 192 + t] = a;
    }
    __syncthreads();  // drains vmcnt before fence
    if (t == 0) {
      __threadfence();
      atomicExch(&flags[(k * 8 + b) * 16], MAGIC);
    }

    if (blk >= 8) return;

    // ======== MLP phase B: fcat for b = blk ========
    int b2_ = blk;
    if (t < 4) {
      while (atomicAdd(&flags[(t * 8 + b2_) * 16], 0) != MAGIC)
        __builtin_amdgcn_s_sleep(2);
    }
    __syncthreads();
    if (t == 0) __threadfence();  // acquire
    __syncthreads();

    float* sc   = smem;          // 576
    float* redb = smem + 576;    // 8*192
    float* shb  = smem + 2112;   // 192
    for (int idx = t; idx < 576; idx += 384) {
      float v;
      if (idx < 192)      v = outs[(0 * 8 + b2_) * 192 + idx];
      else if (idx < 384) v = outs[(1 * 8 + b2_) * 192 + (idx - 192)];
      else                v = outs[(2 * 8 + b2_) * 192 + (idx - 384)] +
                              outs[(3 * 8 + b2_) * 192 + (idx - 384)];
      sc[idx] = v;
    }
    __syncthreads();
    {
      int q = t % 48, s = t / 48;
      {  // 576 -> 192
        const float4* w = (const float4*)fw1;
        float4 acc = {0.f, 0.f, 0.f, 0.f};
        int i0 = s * 72;
        for (int r = 0; r < 4; ++r) {
          float4 wv[18];
#pragma unroll
          for (int j = 0; j < 18; ++j)
            wv[j] = w[(size_t)(i0 + r * 18 + j) * 48 + q];
#pragma unroll
          for (int j = 0; j < 18; ++j) {
            float v = sc[i0 + r * 18 + j];
            acc.x = fmaf(v, wv[j].x, acc.x); acc.y = fmaf(v, wv[j].y, acc.y);
            acc.z = fmaf(v, wv[j].z, acc.z); acc.w = fmaf(v, wv[j].w, acc.w);
          }
        }
        ((float4*)(redb + s * 192))[q] = acc;
      }
      __syncthreads();
      if (t < 192) {
        float a = fb1[t];
#pragma unroll
        for (int s2 = 0; s2 < 8; ++s2) a += redb[s2 * 192 + t];
        shb[t] = fmaxf(a, 0.f);
      }
      __syncthreads();
      {  // 192 -> 192
        const float4* w = (const float4*)fw2;
        float4 acc = {0.f, 0.f, 0.f, 0.f};
        int i0 = s * 24;
        for (int r = 0; r < 2; ++r) {
          float4 wv[12];
#pragma unroll
          for (int j = 0; j < 12; ++j)
            wv[j] = w[(size_t)(i0 + r * 12 + j) * 48 + q];
#pragma unroll
          for (int j = 0; j < 12; ++j) {
            float v = shb[i0 + r * 12 + j];
            acc.x = fmaf(v, wv[j].x, acc.x); acc.y = fmaf(v, wv[j].y, acc.y);
            acc.z = fmaf(v, wv[j].z, acc.z); acc.w = fmaf(v, wv[j].w, acc.w);
          }
        }
        ((float4*)(redb + s * 192))[q] = acc;
      }
      __syncthreads();
      if (t < 192) {
        float a = fb2[t];
#pragma unroll
        for (int s2 = 0; s2 < 8; ++s2) a += redb[s2 * 192 + t];
        param[b2_ * 192 + t] = a;
      }
    }
    __syncthreads();
    if (t == 0) {
      __threadfence();
      atomicExch(&flags[(32 + b2_) * 16], MAGIC);
    }
    return;
  }

  // ======== Render blocks ========
  int rblk = blk - 32;
  int b = rblk / 43, chunk = rblk - b * 43;
  int s4 = chunk * 384 + t;
  bool act = s4 < (HWSZ / 4);

  // prefetch x while the MLP runs
  const float* xb = x + (size_t)b * PLANE;
  float4 vr = {0,0,0,0}, vg = {0,0,0,0}, vb = {0,0,0,0};
  if (act) {
    vr = ((const float4*)(xb))[s4];
    vg = ((const float4*)(xb + HWSZ))[s4];
    vb = ((const float4*)(xb + 2 * HWSZ))[s4];
  }

  if (t == 0) {
    while (atomicAdd(&flags[(32 + b) * 16], 0) != MAGIC)
      __builtin_amdgcn_s_sleep(2);
    __threadfence();  // acquire
  }
  __syncthreads();

  // LUT: e[k] = {S_k*norm/64, p_k*norm}; wave-parallel prefix scan
  float2* tab = (float2*)smem;  // 576 float2
  {
    int wave = t >> 6, lane = t & 63;
    for (int cur = wave; cur < 9; cur += 6) {
      int oi = cur / 3, c = cur - oi * 3;
      const float* src = (oi == 0) ? param + b * 192 + c * 64
                                   : outs + ((oi - 1) * 8 + b) * 192 + c * 64;
      float p = src[lane];
      float v = p;
#pragma unroll
      for (int d = 1; d < 64; d <<= 1) {
        float n = __shfl_up(v, d, 64);
        if (lane >= d) v += n;
      }
      float total = __shfl(v, 63, 64);
      float norm = 64.f / (total + 1e-30f);
      tab[cur * 64 + lane] = make_float2((v - p) * 0.015625f * norm, p * norm);
    }
  }
  __syncthreads();

  if (!act) return;

  auto ev = [&](int cur, float v) -> float {
    int k = (int)(v * 64.f);
    k = k < 0 ? 0 : (k > 63 ? 63 : k);
    float2 e = tab[cur * 64 + k];
    float tt = v - (float)k * 0.015625f;
    return fmaf(tt, e.y, e.x);
  };
  auto ev4 = [&](int cur, float4 v) -> float4 {
    float4 r;
    r.x = ev(cur, v.x); r.y = ev(cur, v.y);
    r.z = ev(cur, v.z); r.w = ev(cur, v.w);
    return r;
  };

  float4 gr;
  gr.x = fmaf(0.299f, vr.x, fmaf(0.587f, vg.x, 0.114f * vb.x));
  gr.y = fmaf(0.299f, vr.y, fmaf(0.587f, vg.y, 0.114f * vb.y));
  gr.z = fmaf(0.299f, vr.z, fmaf(0.587f, vg.z, 0.114f * vb.z));
  gr.w = fmaf(0.299f, vr.w, fmaf(0.587f, vg.w, 0.114f * vb.w));

  float* o0 = out + (size_t)b * PLANE;
  float* o1 = out + OUTSTRIDE + (size_t)b * PLANE;
  float* o2 = out + 2 * OUTSTRIDE + (size_t)b * PLANE;

  ((float4*)(o0))[s4]            = ev4(0, vr);
  ((float4*)(o0 + HWSZ))[s4]     = ev4(1, vg);
  ((float4*)(o0 + 2 * HWSZ))[s4] = ev4(2, vb);
  ((float4*)(o1))[s4]            = ev4(3, gr);
  ((float4*)(o1 + HWSZ))[s4]     = ev4(4, gr);
  ((float4*)(o1 + 2 * HWSZ))[s4] = ev4(5, gr);
  ((float4*)(o2))[s4]            = ev4(6, gr);
  ((float4*)(o2 + HWSZ))[s4]     = ev4(7, gr);
  ((float4*)(o2 + 2 * HWSZ))[s4] = ev4(8, gr);
}

// ---------------------------------------------------------------------------
extern "C" void kernel_launch(void* const* d_in, const int* in_sizes, int n_in,
                              void* d_out, int out_size, void* d_ws, size_t ws_size,
                              hipStream_t stream) {
  const float* x   = (const float*)d_in[0];
  const float* f   = (const float*)d_in[1];
  const float* bf  = (const float*)d_in[2];
  const float* pw1 = (const float*)d_in[3];
  const float* pb1 = (const float*)d_in[4];
  const float* pw2 = (const float*)d_in[5];
  const float* pb2 = (const float*)d_in[6];
  const float* fw1 = (const float*)d_in[7];
  const float* fb1 = (const float*)d_in[8];
  const float* fw2 = (const float*)d_in[9];
  const float* fb2 = (const float*)d_in[10];
  float* out = (float*)d_out;
  float* ws  = (float*)d_ws;

  k_fused<<<376, 384, 0, stream>>>(f, bf, pw1, pb1, pw2, pb2, fw1, fb1, fw2,
                                   fb2, x, out, ws);
}

// Round 10
// 101.801 us; speedup vs baseline: 1.0670x; 1.0670x over previous
//
#include <hip/hip_runtime.h>

// Problem constants
#define HWSZ 65536             // 256*256
#define PLANE (3 * HWSZ)       // one batch's [3,H,W]
#define OUTSTRIDE (8 * PLANE)  // one full output tensor [8,3,256,256]
#define MAGIC 0x13572468       // != 0xAAAAAAAA ws poison

// ---------------------------------------------------------------------------
// Fused MLP: 32 blocks x 384. Blocks 0..31 run proj for (k,b) -> outs, flag;
// blocks 0..7 then spin on 4 flags and run fcat for b -> param.
// Intra-kernel handshake among 32 co-resident blocks (proven in R5/R9).
__global__ __launch_bounds__(384) void k_mlp(
    const float* __restrict__ f, const float* __restrict__ bf,
    const float* __restrict__ pw1, const float* __restrict__ pb1,
    const float* __restrict__ pw2, const float* __restrict__ pb2,
    const float* __restrict__ fw1, const float* __restrict__ fb1,
    const float* __restrict__ fw2, const float* __restrict__ fb2,
    float* __restrict__ ws) {
  __shared__ float smem[2304];
  int t = threadIdx.x, blk = blockIdx.x;

  float* outs  = ws;               // [4,8,192]
  float* param = ws + 6144;        // [8,192]
  int* flags = (int*)(ws + 8192);  // flag_outs[i] = flags[i*16]

  // ======== phase A: proj for (k,b) ========
  int k = blk >> 3, b = blk & 7;
  int q = t % 48, s = t / 48;  // s in 0..7
  {
    float* sf  = smem;         // 512
    float* red = smem + 512;   // 8*192
    float* sh  = smem + 2048;  // 192

    const float* feat = ((k & 1) ? bf : f) + b * 512;
    for (int i = t; i < 512; i += 384) sf[i] = feat[i];
    __syncthreads();

    {  // 512 -> 192
      const float4* w = (const float4*)(pw1 + (size_t)k * (512 * 192));
      float4 acc = {0.f, 0.f, 0.f, 0.f};
      int i0 = s * 64;
      for (int r = 0; r < 4; ++r) {
        float4 wv[16];
#pragma unroll
        for (int j = 0; j < 16; ++j)
          wv[j] = w[(size_t)(i0 + r * 16 + j) * 48 + q];
#pragma unroll
        for (int j = 0; j < 16; ++j) {
          float v = sf[i0 + r * 16 + j];
          acc.x = fmaf(v, wv[j].x, acc.x); acc.y = fmaf(v, wv[j].y, acc.y);
          acc.z = fmaf(v, wv[j].z, acc.z); acc.w = fmaf(v, wv[j].w, acc.w);
        }
      }
      ((float4*)(red + s * 192))[q] = acc;
    }
    __syncthreads();
    if (t < 192) {
      float a = pb1[k * 192 + t];
#pragma unroll
      for (int s2 = 0; s2 < 8; ++s2) a += red[s2 * 192 + t];
      sh[t] = fmaxf(a, 0.f);
    }
    __syncthreads();
    {  // 192 -> 192
      const float4* w = (const float4*)(pw2 + (size_t)k * (192 * 192));
      float4 acc = {0.f, 0.f, 0.f, 0.f};
      int i0 = s * 24;
      for (int r = 0; r < 2; ++r) {
        float4 wv[12];
#pragma unroll
        for (int j = 0; j < 12; ++j)
          wv[j] = w[(size_t)(i0 + r * 12 + j) * 48 + q];
#pragma unroll
        for (int j = 0; j < 12; ++j) {
          float v = sh[i0 + r * 12 + j];
          acc.x = fmaf(v, wv[j].x, acc.x); acc.y = fmaf(v, wv[j].y, acc.y);
          acc.z = fmaf(v, wv[j].z, acc.z); acc.w = fmaf(v, wv[j].w, acc.w);
        }
      }
      ((float4*)(red + s * 192))[q] = acc;
    }
    __syncthreads();
    if (t < 192) {
      float a = pb2[k * 192 + t];
#pragma unroll
      for (int s2 = 0; s2 < 8; ++s2) a += red[s2 * 192 + t];
      outs[(k * 8 + b) * 192 + t] = a;
    }
    __syncthreads();  // drain vmcnt before fence
    if (t == 0) {
      __threadfence();
      atomicExch(&flags[(k * 8 + b) * 16], MAGIC);
    }
  }

  if (blk >= 8) return;

  // ======== phase B: fcat for b = blk ========
  int b2 = blk;
  if (t < 4) {
    while (atomicAdd(&flags[(t * 8 + b2) * 16], 0) != MAGIC)
      __builtin_amdgcn_s_sleep(2);
  }
  __syncthreads();
  if (t == 0) __threadfence();  // acquire
  __syncthreads();

  float* sc   = smem;          // 576
  float* redb = smem + 576;    // 8*192
  float* shb  = smem + 2112;   // 192
  for (int idx = t; idx < 576; idx += 384) {
    float v;
    if (idx < 192)      v = outs[(0 * 8 + b2) * 192 + idx];
    else if (idx < 384) v = outs[(1 * 8 + b2) * 192 + (idx - 192)];
    else                v = outs[(2 * 8 + b2) * 192 + (idx - 384)] +
                            outs[(3 * 8 + b2) * 192 + (idx - 384)];
    sc[idx] = v;
  }
  __syncthreads();
  {  // 576 -> 192
    const float4* w = (const float4*)fw1;
    float4 acc = {0.f, 0.f, 0.f, 0.f};
    int i0 = s * 72;
    for (int r = 0; r < 4; ++r) {
      float4 wv[18];
#pragma unroll
      for (int j = 0; j < 18; ++j)
        wv[j] = w[(size_t)(i0 + r * 18 + j) * 48 + q];
#pragma unroll
      for (int j = 0; j < 18; ++j) {
        float v = sc[i0 + r * 18 + j];
        acc.x = fmaf(v, wv[j].x, acc.x); acc.y = fmaf(v, wv[j].y, acc.y);
        acc.z = fmaf(v, wv[j].z, acc.z); acc.w = fmaf(v, wv[j].w, acc.w);
      }
    }
    ((float4*)(redb + s * 192))[q] = acc;
  }
  __syncthreads();
  if (t < 192) {
    float a = fb1[t];
#pragma unroll
    for (int s2 = 0; s2 < 8; ++s2) a += redb[s2 * 192 + t];
    shb[t] = fmaxf(a, 0.f);
  }
  __syncthreads();
  {  // 192 -> 192
    const float4* w = (const float4*)fw2;
    float4 acc = {0.f, 0.f, 0.f, 0.f};
    int i0 = s * 24;
    for (int r = 0; r < 2; ++r) {
      float4 wv[12];
#pragma unroll
      for (int j = 0; j < 12; ++j)
        wv[j] = w[(size_t)(i0 + r * 12 + j) * 48 + q];
#pragma unroll
      for (int j = 0; j < 12; ++j) {
        float v = shb[i0 + r * 12 + j];
        acc.x = fmaf(v, wv[j].x, acc.x); acc.y = fmaf(v, wv[j].y, acc.y);
        acc.z = fmaf(v, wv[j].z, acc.z); acc.w = fmaf(v, wv[j].w, acc.w);
      }
    }
    ((float4*)(redb + s * 192))[q] = acc;
  }
  __syncthreads();
  if (t < 192) {
    float a = fb2[t];
#pragma unroll
    for (int s2 = 0; s2 < 8; ++s2) a += redb[s2 * 192 + t];
    param[b2 * 192 + t] = a;
  }
}

// ---------------------------------------------------------------------------
// Render. LUT entry e[k] = {S_k*norm/64, p_k*norm}; eval = one b64 LDS gather
// + one FMA. LUT built with a per-wave prefix scan (width-64 shfl_up).
__global__ __launch_bounds__(256) void k_render(
    const float* __restrict__ x, const float* __restrict__ ws,
    float* __restrict__ out) {
  int b = blockIdx.y, t = threadIdx.x;
  int wave = t >> 6, lane = t & 63;
  const float* outs  = ws;
  const float* param = ws + 6144;
  __shared__ float2 tab[576];

  for (int cur = wave; cur < 9; cur += 4) {
    int oi = cur / 3, c = cur - oi * 3;
    const float* src = (oi == 0) ? param + b * 192 + c * 64
                                 : outs + ((oi - 1) * 8 + b) * 192 + c * 64;
    float p = src[lane];
    float v = p;  // inclusive scan
#pragma unroll
    for (int d = 1; d < 64; d <<= 1) {
      float n = __shfl_up(v, d, 64);
      if (lane >= d) v += n;
    }
    float total = __shfl(v, 63, 64);
    float norm = 64.f / (total + 1e-30f);
    tab[cur * 64 + lane] = make_float2((v - p) * 0.015625f * norm, p * norm);
  }
  __syncthreads();

  auto ev = [&](int cur, float v) -> float {
    int k = (int)(v * 64.f);
    k = k < 0 ? 0 : (k > 63 ? 63 : k);
    float2 e = tab[cur * 64 + k];
    float tt = v - (float)k * 0.015625f;
    return fmaf(tt, e.y, e.x);
  };
  auto ev4 = [&](int cur, float4 v) -> float4 {
    float4 r;
    r.x = ev(cur, v.x); r.y = ev(cur, v.y);
    r.z = ev(cur, v.z); r.w = ev(cur, v.w);
    return r;
  };

  int s4 = blockIdx.x * 256 + t;
  const float* xb = x + (size_t)b * PLANE;
  float4 vr = ((const float4*)(xb))[s4];
  float4 vg = ((const float4*)(xb + HWSZ))[s4];
  float4 vb = ((const float4*)(xb + 2 * HWSZ))[s4];

  float4 gr;
  gr.x = fmaf(0.299f, vr.x, fmaf(0.587f, vg.x, 0.114f * vb.x));
  gr.y = fmaf(0.299f, vr.y, fmaf(0.587f, vg.y, 0.114f * vb.y));
  gr.z = fmaf(0.299f, vr.z, fmaf(0.587f, vg.z, 0.114f * vb.z));
  gr.w = fmaf(0.299f, vr.w, fmaf(0.587f, vg.w, 0.114f * vb.w));

  float* o0 = out + (size_t)b * PLANE;
  float* o1 = out + OUTSTRIDE + (size_t)b * PLANE;
  float* o2 = out + 2 * OUTSTRIDE + (size_t)b * PLANE;

  ((float4*)(o0))[s4]            = ev4(0, vr);
  ((float4*)(o0 + HWSZ))[s4]     = ev4(1, vg);
  ((float4*)(o0 + 2 * HWSZ))[s4] = ev4(2, vb);
  ((float4*)(o1))[s4]            = ev4(3, gr);
  ((float4*)(o1 + HWSZ))[s4]     = ev4(4, gr);
  ((float4*)(o1 + 2 * HWSZ))[s4] = ev4(5, gr);
  ((float4*)(o2))[s4]            = ev4(6, gr);
  ((float4*)(o2 + HWSZ))[s4]     = ev4(7, gr);
  ((float4*)(o2 + 2 * HWSZ))[s4] = ev4(8, gr);
}

// ---------------------------------------------------------------------------
extern "C" void kernel_launch(void* const* d_in, const int* in_sizes, int n_in,
                              void* d_out, int out_size, void* d_ws, size_t ws_size,
                              hipStream_t stream) {
  const float* x   = (const float*)d_in[0];
  const float* f   = (const float*)d_in[1];
  const float* bf  = (const float*)d_in[2];
  const float* pw1 = (const float*)d_in[3];
  const float* pb1 = (const float*)d_in[4];
  const float* pw2 = (const float*)d_in[5];
  const float* pb2 = (const float*)d_in[6];
  const float* fw1 = (const float*)d_in[7];
  const float* fb1 = (const float*)d_in[8];
  const float* fw2 = (const float*)d_in[9];
  const float* fb2 = (const float*)d_in[10];
  float* out = (float*)d_out;
  float* ws  = (float*)d_ws;

  k_mlp<<<32, 384, 0, stream>>>(f, bf, pw1, pb1, pw2, pb2, fw1, fb1, fw2,
                                fb2, ws);
  dim3 grid(64, 8);
  k_render<<<grid, 256, 0, stream>>>(x, ws, out);
}